// Round 8
// baseline (166.156 us; speedup 1.0000x reference)
//
#include <hip/hip_runtime.h>
#include <hip/hip_bf16.h>
#include <float.h>

// B=4096, D=512, N=8192, temp=0.5
#define BN_ 4096
#define DD  512
#define NN  8192
#define SCALE 2.0f   // 1/temperature

typedef unsigned short u16;
typedef __attribute__((ext_vector_type(8))) short short8;   // 8 bf16 = 4 VGPRs
typedef __attribute__((ext_vector_type(4))) float floatx4;  // MFMA acc

struct alignas(8) U16x4 { u16 x, y, z, w; };

__device__ __forceinline__ u16 f2bf(float f) {
    union { float f; unsigned u; } c; c.f = f;
    unsigned u = c.u;
    unsigned r = (u + 0x7fffu + ((u >> 16) & 1u)) >> 16;   // RNE
    return (u16)r;
}

__device__ __forceinline__ void async_copy16(const u16* g, u16* l) {
    __builtin_amdgcn_global_load_lds(
        (const __attribute__((address_space(1))) void*)g,
        (__attribute__((address_space(3))) void*)l, 16, 0, 0);
}

// ------ kernel 1: fp32 -> bf16 concat + per-block positive-dot partial ------
// No atomics: block partial -> Pos[bid]; block 0 zero-inits d_out.
__global__ __launch_bounds__(256) void convert_pos_kernel(const float* __restrict__ hi,
                                                          const float* __restrict__ hj,
                                                          u16* __restrict__ H,
                                                          float* __restrict__ Pos,
                                                          float* __restrict__ out) {
    __shared__ float red[4];
    int t = blockIdx.x * 256 + threadIdx.x;     // 2048 blocks -> 524288 threads
    int e = t * 4;
    const int BD = BN_ * DD;
    float4 a = *(const float4*)(hi + e);
    float4 b = *(const float4*)(hj + e);
    U16x4 oa, ob;
    oa.x = f2bf(a.x); oa.y = f2bf(a.y); oa.z = f2bf(a.z); oa.w = f2bf(a.w);
    ob.x = f2bf(b.x); ob.y = f2bf(b.y); ob.z = f2bf(b.z); ob.w = f2bf(b.w);
    *(U16x4*)(H + e) = oa;
    *(U16x4*)(H + BD + e) = ob;
    float dot = a.x * b.x + a.y * b.y + a.z * b.z + a.w * b.w;
#pragma unroll
    for (int msk = 1; msk < 64; msk <<= 1) dot += __shfl_xor(dot, msk);
    int lane = threadIdx.x & 63, wid = threadIdx.x >> 6;
    if (lane == 0) red[wid] = dot;
    __syncthreads();
    if (threadIdx.x == 0) {
        Pos[blockIdx.x] = red[0] + red[1] + red[2] + red[3];
        if (blockIdx.x == 0) *out = 0.0f;
    }
}

// ------------- kernel 2: symmetric Gram, lower-triangle 128x128 tiles -------------
// R3 grid/epilogue, new K-loop: A fragments loaded DIRECT from global (16 full
// 64B lines per instr, issued at the top of the K-step, consumed after B
// staging + ds_reads are queued -> latency hidden by 3 blocks/CU). B stays in
// LDS (2x cross-wave reuse), DOUBLE-buffered, one barrier per K-step. ds_read
// traffic halves vs R3 (64->32 KB per block-K-step). LDS chunk (row,kc)
// XOR-swizzled at slot row*8 + (kc ^ (row&7)) via the source pointer.
__global__ __launch_bounds__(256, 3) void gram_kernel(const u16* __restrict__ H,
                                                      float* __restrict__ Mpart,
                                                      float* __restrict__ Spart) {
    __shared__ u16 Bs[2][128 * 64];            // 2 x 16 KB
    __shared__ float Rm[2][128], Rs[2][128];   // row partials per wc
    __shared__ float Cm[2][128], Cs[2][128];   // col partials per wr

    const int tid  = threadIdx.x;
    const int lane = tid & 63;
    const int wid  = tid >> 6;
    const int quad = lane >> 4;
    const int ln15 = lane & 15;
    const int wr = wid >> 1, wc = wid & 1;

    // lower-triangle decode: blockIdx.x in [0, 2080)
    int t = blockIdx.x;
    int bi = (int)((sqrtf(8.0f * (float)t + 1.0f) - 1.0f) * 0.5f);
    while ((bi + 1) * (bi + 2) / 2 <= t) bi++;
    while (bi * (bi + 1) / 2 > t) bi--;
    const int bj = t - bi * (bi + 1) / 2;
    const bool diag = (bi == bj);
    const int biBase = bi * 128, bjBase = bj * 128;

    // B staging pointers (1024 chunks, 4 rounds of 256 threads)
    const u16* srcB[4];
    int dstB[4];
#pragma unroll
    for (int j = 0; j < 4; j++) {
        int c   = j * 256 + tid;        // chunk 0..1023
        int row = c >> 3;               // 0..127
        int kc  = (c & 7) ^ (row & 7);  // swizzle inverse on source side
        srcB[j] = H + (size_t)(bjBase + row) * DD + kc * 8;
        dstB[j] = c * 8;
    }

    // A direct-load row pointers: ln15 -> row, quad -> 16B k-chunk
    const u16* aRow[4];
#pragma unroll
    for (int tm = 0; tm < 4; tm++)
        aRow[tm] = H + (size_t)(biBase + wr * 64 + tm * 16 + ln15) * DD + quad * 8;

    floatx4 acc[4][4];
#pragma unroll
    for (int i = 0; i < 4; i++)
#pragma unroll
        for (int j = 0; j < 4; j++) acc[i][j] = (floatx4)0.0f;

    // prefetch B(0) into buffer 0
#pragma unroll
    for (int j = 0; j < 4; j++) async_copy16(srcB[j], &Bs[0][dstB[j]]);

    for (int i = 0; i < 8; i++) {
        __syncthreads();                 // B(i) resident (drains our staging)
        const int k0 = i * 64;
        // A fragment loads for the whole K-step, issued first
        short8 a[2][4];
#pragma unroll
        for (int kk = 0; kk < 2; kk++)
#pragma unroll
            for (int tm = 0; tm < 4; tm++)
                a[kk][tm] = *(const short8*)(aRow[tm] + k0 + kk * 32);
        // B(i+1) staging into the other buffer
        if (i < 7) {
            const int nxt = (i + 1) & 1;
#pragma unroll
            for (int j = 0; j < 4; j++)
                async_copy16(srcB[j] + k0 + 64, &Bs[nxt][dstB[j]]);
        }
        const u16* bs = Bs[i & 1];
#pragma unroll
        for (int kk = 0; kk < 2; kk++) {
            int ck = kk * 4 + quad;      // K-chunk 0..7
            short8 b[4];
#pragma unroll
            for (int tn = 0; tn < 4; tn++) {
                int r = wc * 64 + tn * 16 + ln15;
                b[tn] = *(const short8*)&bs[(r * 8 + (ck ^ (r & 7))) * 8];
            }
#pragma unroll
            for (int tm = 0; tm < 4; tm++)
#pragma unroll
                for (int tn = 0; tn < 4; tn++)
                    acc[tm][tn] = __builtin_amdgcn_mfma_f32_16x16x32_bf16(
                        a[kk][tm], b[tn], acc[tm][tn], 0, 0, 0);
        }
    }

    // scale in place; mask self-similarity on diagonal tiles
    // C/D layout: local row = tm*16 + quad*4 + reg, local col = tn*16 + ln15
#pragma unroll
    for (int tm = 0; tm < 4; tm++)
#pragma unroll
        for (int tn = 0; tn < 4; tn++)
#pragma unroll
            for (int r = 0; r < 4; r++) {
                float v = SCALE * acc[tm][tn][r];
                if (diag) {
                    int lrow = wr * 64 + tm * 16 + quad * 4 + r;
                    int lcol = wc * 64 + tn * 16 + ln15;
                    if (lrow == lcol) v = -FLT_MAX;
                }
                acc[tm][tn][r] = v;
            }

    // row pass: per-row max+sumexp over this wave's 64 cols
#pragma unroll
    for (int tm = 0; tm < 4; tm++) {
#pragma unroll
        for (int r = 0; r < 4; r++) {
            float vmax = -FLT_MAX;
#pragma unroll
            for (int tn = 0; tn < 4; tn++) vmax = fmaxf(vmax, acc[tm][tn][r]);
#pragma unroll
            for (int msk = 1; msk < 16; msk <<= 1)
                vmax = fmaxf(vmax, __shfl_xor(vmax, msk));
            float s = 0.0f;
#pragma unroll
            for (int tn = 0; tn < 4; tn++) s += __expf(acc[tm][tn][r] - vmax);
#pragma unroll
            for (int msk = 1; msk < 16; msk <<= 1) s += __shfl_xor(s, msk);
            if (ln15 == 0) {
                int x = wr * 64 + tm * 16 + quad * 4 + r;
                Rm[wc][x] = vmax; Rs[wc][x] = s;
            }
        }
    }

    // col pass (transpose tile): per-col max+sumexp over this wave's 64 rows
    if (!diag) {
#pragma unroll
        for (int tn = 0; tn < 4; tn++) {
            float cm = -FLT_MAX;
#pragma unroll
            for (int tm = 0; tm < 4; tm++)
#pragma unroll
                for (int r = 0; r < 4; r++) cm = fmaxf(cm, acc[tm][tn][r]);
            cm = fmaxf(cm, __shfl_xor(cm, 16));
            cm = fmaxf(cm, __shfl_xor(cm, 32));
            float s = 0.0f;
#pragma unroll
            for (int tm = 0; tm < 4; tm++)
#pragma unroll
                for (int r = 0; r < 4; r++) s += __expf(acc[tm][tn][r] - cm);
            s += __shfl_xor(s, 16);
            s += __shfl_xor(s, 32);
            if (quad == 0) {
                int y = wc * 64 + tn * 16 + ln15;
                Cm[wr][y] = cm; Cs[wr][y] = s;
            }
        }
    }
    __syncthreads();

    // merge wave halves, write slot-major partials: Mpart[slot*NN + globalRow]
    if (tid < 128) {
        float m0 = Rm[0][tid], m1 = Rm[1][tid];
        float s0 = Rs[0][tid], s1 = Rs[1][tid];
        float m = fmaxf(m0, m1);
        float s = s0 * __expf(m0 - m) + s1 * __expf(m1 - m);
        Mpart[(size_t)bj * NN + biBase + tid] = m;
        Spart[(size_t)bj * NN + biBase + tid] = s;
    } else if (!diag) {
        int y = tid - 128;
        float m0 = Cm[0][y], m1 = Cm[1][y];
        float s0 = Cs[0][y], s1 = Cs[1][y];
        float m = fmaxf(m0, m1);
        float s = s0 * __expf(m0 - m) + s1 * __expf(m1 - m);
        Mpart[(size_t)bi * NN + bjBase + y] = m;
        Spart[(size_t)bi * NN + bjBase + y] = s;
    }
}

// ------ kernel 3: combine 64 slot-partials per row + pos partials -> loss ------
__global__ __launch_bounds__(256) void lse_kernel(const float* __restrict__ Mpart,
                                                  const float* __restrict__ Spart,
                                                  const float* __restrict__ Pos,
                                                  float* __restrict__ out) {
    __shared__ float red[256];
    int tid = threadIdx.x;
    int r = blockIdx.x * 256 + tid;            // 32 blocks x 256 rows
    float m = -FLT_MAX, s = 0.0f;
#pragma unroll 8
    for (int c = 0; c < 64; c++) {
        float mc = Mpart[(size_t)c * NN + r];  // coalesced: lane-stride 4B
        float sc = Spart[(size_t)c * NN + r];
        float mn = fmaxf(m, mc);
        s = s * __expf(m - mn) + sc * __expf(mc - mn);
        m = mn;
    }
    float v = m + logf(s);
    if (tid < 64) v += -4.0f * Pos[blockIdx.x * 64 + tid];
    red[tid] = v;
    __syncthreads();
    for (int st = 128; st > 0; st >>= 1) {
        if (tid < st) red[tid] += red[tid + st];
        __syncthreads();
    }
    if (tid == 0) atomicAdd(out, red[0] * (1.0f / (float)NN));
}

extern "C" void kernel_launch(void* const* d_in, const int* in_sizes, int n_in,
                              void* d_out, int out_size, void* d_ws, size_t ws_size,
                              hipStream_t stream) {
    const float* hi = (const float*)d_in[0];
    const float* hj = (const float*)d_in[1];
    float* out = (float*)d_out;

    u16*   H     = (u16*)d_ws;                                            // 8 MB
    float* Mpart = (float*)((char*)d_ws + (size_t)8 * 1024 * 1024);       // 2 MB
    float* Spart = (float*)((char*)d_ws + (size_t)10 * 1024 * 1024);      // 2 MB
    float* Pos   = (float*)((char*)d_ws + (size_t)12 * 1024 * 1024);      // 8 KB

    convert_pos_kernel<<<2048, 256, 0, stream>>>(hi, hj, H, Pos, out);

    gram_kernel<<<2080, 256, 0, stream>>>(H, Mpart, Spart);   // 65*64/2 tiles

    lse_kernel<<<32, 256, 0, stream>>>(Mpart, Spart, Pos, out);
}